// Round 8
// baseline (392.958 us; speedup 1.0000x reference)
//
#include <hip/hip_runtime.h>

// HGNN conv: out = degv ⊙ (H @ ((w*deg_e) ⊙ (H^T @ (degv ⊙ (x@W))))) + bias ; w = sigmoid(H^T (x V))
// N=8192, E=4096, F=512. R19: PAD LEADING DIMENSIONS to break power-of-2 channel aliasing.
// Evidence R11-R18: every strided-tile kernel (any granule 64-256B, read- or write-side)
// pins at ~2.5 TB/s while linear streams hit 6.3-6.9 TB/s. Common factor: 8/16 KB
// power-of-2 row pitches -> same-channel aliasing. Fix: Hbf ld 4096->4128 u16,
// HTbf/doutT 8192->8224, t2T 4096->4128 (+64B/row channel rotation; 16B alignment kept).
// Applies to prep stores, degv reads, and all GEMM A/B row staging. Pipeline = R14-best
// (prep_h4) + neutral dispatch merges.

#define N_NODES 8192
#define N_EDGES 4096
#define FT 512
#define LDH  4128    // Hbf leading dim (u16)
#define LDHT 8224    // HTbf leading dim (u16)
#define LDD  8224    // doutT leading dim (u16)
#define LDT  4128    // t2T leading dim (u16)

typedef short bf16x8 __attribute__((ext_vector_type(8)));
typedef float f32x4 __attribute__((ext_vector_type(4)));
typedef unsigned short u16;
typedef unsigned int u32;

__device__ __forceinline__ u16 f2b(float f) {
    union { float f; u32 u; } v; v.f = f;
    u32 r = v.u + 0x7FFFu + ((v.u >> 16) & 1u);   // RNE
    return (u16)(r >> 16);
}
__device__ __forceinline__ float b2f(u16 h) {
    union { u32 u; float f; } v; v.u = ((u32)h) << 16; return v.f;
}

// ---------------- scalar-path kernels ----------------

// xv[n] = x[n,:] . V ; xb = bf16(x) ; blocks 0..31 zero zsum+desum (8192 f contiguous)
__global__ __launch_bounds__(256) void xv_xb_kernel(const float* __restrict__ x,
                                                    const float* __restrict__ V,
                                                    float* __restrict__ xv,
                                                    u16* __restrict__ xb,
                                                    float* __restrict__ zd) {
    if (blockIdx.x < 32) zd[blockIdx.x * 256 + threadIdx.x] = 0.f;
    int row = blockIdx.x * 4 + (threadIdx.x >> 6);
    int lane = threadIdx.x & 63;
    const float* xr = x + (size_t)row * FT + lane * 8;
    const float* vr = V + lane * 8;
    float4 a0 = *(const float4*)xr, a1 = *(const float4*)(xr + 4);
    float4 b0 = *(const float4*)vr, b1 = *(const float4*)(vr + 4);
    float acc = a0.x * b0.x + a0.y * b0.y + a0.z * b0.z + a0.w * b0.w +
                a1.x * b1.x + a1.y * b1.y + a1.z * b1.z + a1.w * b1.w;
    u16 tmp[8] = {f2b(a0.x), f2b(a0.y), f2b(a0.z), f2b(a0.w),
                  f2b(a1.x), f2b(a1.y), f2b(a1.z), f2b(a1.w)};
    *(uint4*)(xb + (size_t)row * FT + lane * 8) = *(uint4*)tmp;
#pragma unroll
    for (int off = 32; off; off >>= 1) acc += __shfl_down(acc, off);
    if (lane == 0) xv[row] = acc;
}

// Fused prep (R14 structure): Hbf = bf16(H); HTbf = Hbf^T; zsum/desum accumulate.
// Phase 1 LDS-only before barrier; Hbf stores post-barrier; padded output strides.
__global__ __launch_bounds__(256) void prep_h4_kernel(const float* __restrict__ H,
                                                      const float* __restrict__ xv,
                                                      u16* __restrict__ Hbf,
                                                      u16* __restrict__ HTbf,
                                                      float* __restrict__ zsum,
                                                      float* __restrict__ desum) {
    __shared__ u32 Wt[64][33];                    // Wt[n][ew] = packed e-pair (2ew, 2ew+1)
    __shared__ float xvs[64];
    const int t = threadIdx.x;
    const int e0 = blockIdx.x * 64, n0 = blockIdx.y * 64;
    if (t < 64) xvs[t] = xv[n0 + t];
    const int n_ld = t >> 2, seg = t & 3;
    u32 o[8];
    {   // phase 1: load/convert; LDS write only
        const float* src = H + (size_t)(n0 + n_ld) * N_EDGES + e0 + seg * 16;
#pragma unroll
        for (int j = 0; j < 4; j++) {
            float4 h = *(const float4*)(src + j * 4);
            o[2 * j]     = (h.x != 0.f ? 0x3F80u : 0u) | (h.y != 0.f ? 0x3F800000u : 0u);
            o[2 * j + 1] = (h.z != 0.f ? 0x3F80u : 0u) | (h.w != 0.f ? 0x3F800000u : 0u);
        }
#pragma unroll
        for (int j = 0; j < 8; j++) Wt[n_ld][seg * 8 + j] = o[j];
    }
    __syncthreads();
    {   // Hbf stores post-barrier (padded ld)
        u16* hdst = Hbf + (size_t)(n0 + n_ld) * LDH + e0 + seg * 16;
        *(uint4*)hdst       = *(uint4*)&o[0];
        *(uint4*)(hdst + 8) = *(uint4*)&o[4];
    }
    {   // phase 2: perm transpose -> HTbf (padded ld) + z/d accumulation
        int e = t >> 2, g = t & 3;
        int ew = e >> 1;
        u32 sel = (e & 1) ? 0x07060302u : 0x05040100u;
        u32 oo[8];
        float z = 0.f, d = 0.f;
#pragma unroll
        for (int j = 0; j < 8; j++) {
            int np = g * 8 + j;
            oo[j] = __builtin_amdgcn_perm(Wt[2 * np + 1][ew], Wt[2 * np][ew], sel);
            z += (oo[j] & 0xFFFFu) ? xvs[2 * np] : 0.f;
            d += (oo[j] & 0xFFFFu) ? 1.f : 0.f;
            z += (oo[j] >> 16) ? xvs[2 * np + 1] : 0.f;
            d += (oo[j] >> 16) ? 1.f : 0.f;
        }
        u32* drow = (u32*)(HTbf + (size_t)(e0 + e) * LDHT + n0);
        *(uint4*)(drow + g * 8)     = *(uint4*)&oo[0];
        *(uint4*)(drow + g * 8 + 4) = *(uint4*)&oo[4];
        z += __shfl_down(z, 2); z += __shfl_down(z, 1);
        d += __shfl_down(d, 2); d += __shfl_down(d, 1);
        if (g == 0) {
            atomicAdd(zsum + e0 + e, z);
            atomicAdd(desum + e0 + e, d);
        }
    }
}

// Merged: blocks 0..15 = sigmoid (w, wde); blocks 16..271 = W -> WT (bf16 transpose)
__global__ __launch_bounds__(256) void sigwt_kernel(const float* __restrict__ zsum,
                                                    const float* __restrict__ desum,
                                                    float* __restrict__ w_out,
                                                    float* __restrict__ wde,
                                                    const float* __restrict__ W,
                                                    u16* __restrict__ WT) {
    __shared__ float tile[32][33];
    int bx = blockIdx.x;
    if (bx < 16) {
        int e = bx * 256 + threadIdx.x;
        float z = zsum[e];
        float wv = 1.f / (1.f + expf(-z));
        w_out[e] = wv;
        wde[e] = wv * desum[e];
    } else {
        int b = bx - 16;
        int bxx = b & 15, byy = b >> 4;
        int tx = threadIdx.x & 31, ty = threadIdx.x >> 5;
        int c = bxx * 32 + tx;
        int r0 = byy * 32;
#pragma unroll
        for (int i = 0; i < 4; i++)
            tile[ty + i * 8][tx] = W[(size_t)(r0 + ty + i * 8) * FT + c];
        __syncthreads();
#pragma unroll
        for (int i = 0; i < 4; i++)
            WT[(size_t)(bxx * 32 + ty + i * 8) * FT + r0 + tx] = f2b(tile[tx][ty + i * 8]);
    }
}

// degv[n] = Hbf[n,:] . w   (one wave per row; padded row pitch)
__global__ __launch_bounds__(256) void degv_kernel(const u16* __restrict__ Hbf,
                                                   const float* __restrict__ w,
                                                   float* __restrict__ degv) {
    int row = blockIdx.x * 4 + (threadIdx.x >> 6);
    int lane = threadIdx.x & 63;
    const uint4* hr = (const uint4*)(Hbf + (size_t)row * LDH);
    float acc = 0.f;
#pragma unroll
    for (int i = 0; i < 8; i++) {
        int idx = i * 64 + lane;
        uint4 h = hr[idx];
        const float* w8 = w + idx * 8;
        float4 wa = *(const float4*)w8, wb = *(const float4*)(w8 + 4);
        acc += (h.x & 0xFFFFu) ? wa.x : 0.f;  acc += (h.x >> 16) ? wa.y : 0.f;
        acc += (h.y & 0xFFFFu) ? wa.z : 0.f;  acc += (h.y >> 16) ? wa.w : 0.f;
        acc += (h.z & 0xFFFFu) ? wb.x : 0.f;  acc += (h.z >> 16) ? wb.y : 0.f;
        acc += (h.w & 0xFFFFu) ? wb.z : 0.f;  acc += (h.w >> 16) ? wb.w : 0.f;
    }
#pragma unroll
    for (int off = 32; off; off >>= 1) acc += __shfl_down(acc, off);
    if (lane == 0) degv[row] = acc;
}

// t2T[f,e] = f2b(wde[e] * sum_{s<8} P[s][e][f])   (padded t2T pitch)
__global__ void t2t_kernel(const u16* __restrict__ P, const float* __restrict__ wde,
                           u16* __restrict__ t2T) {
    __shared__ float tile[32][33];
    int tx = threadIdx.x, ty = threadIdx.y;
    int f0 = blockIdx.x * 32, e0 = blockIdx.y * 32;
#pragma unroll
    for (int i = 0; i < 4; i++) {
        int e = e0 + ty + i * 8;
        size_t idx = (size_t)e * 512 + f0 + tx;
        float s = 0.f;
#pragma unroll
        for (int sl = 0; sl < 8; sl++)
            s += b2f(P[idx + (size_t)sl * N_EDGES * 512]);
        tile[ty + i * 8][tx] = wde[e] * s;
    }
    __syncthreads();
#pragma unroll
    for (int i = 0; i < 4; i++)
        t2T[(size_t)(f0 + ty + i * 8) * LDT + e0 + tx] = f2b(tile[tx][ty + i * 8]);
}

// out[n,f] = degv[n]*sum_{s<4} P[s][n][f] + bias[f]
__global__ __launch_bounds__(256) void final_kernel(const u16* __restrict__ P,
                                                    const float* __restrict__ degv,
                                                    const float* __restrict__ bias,
                                                    float* __restrict__ out) {
    int i8 = blockIdx.x * 256 + threadIdx.x;
    int base = i8 * 8;
    int n = base >> 9, f = base & 511;
    float s[8] = {0.f, 0.f, 0.f, 0.f, 0.f, 0.f, 0.f, 0.f};
#pragma unroll
    for (int sl = 0; sl < 4; sl++) {
        uint4 v = *(const uint4*)(P + (size_t)sl * N_NODES * 512 + base);
        u32 ws[4] = {v.x, v.y, v.z, v.w};
#pragma unroll
        for (int j = 0; j < 4; j++) {
            s[2 * j]     += b2f((u16)(ws[j] & 0xFFFFu));
            s[2 * j + 1] += b2f((u16)(ws[j] >> 16));
        }
    }
    float dv = degv[n];
    float4 o0, o1;
    o0.x = dv * s[0] + bias[f + 0]; o0.y = dv * s[1] + bias[f + 1];
    o0.z = dv * s[2] + bias[f + 2]; o0.w = dv * s[3] + bias[f + 3];
    o1.x = dv * s[4] + bias[f + 4]; o1.y = dv * s[5] + bias[f + 5];
    o1.z = dv * s[6] + bias[f + 6]; o1.w = dv * s[7] + bias[f + 7];
    *(float4*)(out + base) = o0;
    *(float4*)(out + base + 4) = o1;
}

// ---------------- MFMA GEMM: TBK=64, full-DMA + rotate-by-row swizzle ----------------
// Tile (MT*32) x (NT*32), 4 waves (2x2). bf16 row-major operands, k-contiguous.
// EPI 0: bf16 partial store at Cp + z*Ssz, ldc-row-major
// EPI 1: bf16 store C[m*ldc+n] scaled by degv[n]

#define TBK 64

template <int MT, int NT, int EPI>
__global__ __launch_bounds__(256, 4)
void gemm9(const u16* __restrict__ Ap, const u16* __restrict__ Bp,
           void* __restrict__ Cp, const float* __restrict__ degv,
           int KC, int lda, int ldb, int ldc, size_t Ssz) {
    __shared__ __align__(16) u16 Alds[MT * 32 * TBK];
    __shared__ __align__(16) u16 Blds[NT * 32 * TBK];
    const int t = threadIdx.x;
    const int m0 = blockIdx.x * (MT * 32), n0 = blockIdx.y * (NT * 32);
    const int kbase = blockIdx.z * KC;
    const int wave = t >> 6, lane = t & 63, quad = lane >> 4, lo = lane & 15;
    const int wm = (wave >> 1) * (MT * 16), wn = (wave & 1) * (NT * 16);

    f32x4 acc[MT][NT];
#pragma unroll
    for (int a = 0; a < MT; a++)
#pragma unroll
        for (int b = 0; b < NT; b++) acc[a][b] = (f32x4){0.f, 0.f, 0.f, 0.f};

    for (int kk = 0; kk < KC; kk += TBK) {
        const int k0 = kbase + kk;
        __syncthreads();
#pragma unroll
        for (int i = 0; i < MT; i++) {            // A: MT*32 rows x 8 chunks
            int c = t + i * 256;
            int r = c >> 3;
            int j = ((c & 7) - r) & 7;
            const u16* g = Ap + (size_t)(m0 + r) * lda + k0 + j * 8;
            __builtin_amdgcn_global_load_lds((const u32*)g, (u32*)(Alds + c * 8), 16, 0, 0);
        }
#pragma unroll
        for (int i = 0; i < NT; i++) {            // B: NT*32 rows x 8 chunks
            int c = t + i * 256;
            int r = c >> 3;
            int j = ((c & 7) - r) & 7;
            const u16* g = Bp + (size_t)(n0 + r) * ldb + k0 + j * 8;
            __builtin_amdgcn_global_load_lds((const u32*)g, (u32*)(Blds + c * 8), 16, 0, 0);
        }
        __syncthreads();

#pragma unroll
        for (int s2 = 0; s2 < 2; s2++) {
            bf16x8 af[MT], bfr[NT];
#pragma unroll
            for (int mt = 0; mt < MT; mt++) {
                int m = wm + mt * 16 + lo;
                int s = (s2 * 4 + quad + m) & 7;
                af[mt] = *(const bf16x8*)&Alds[m * TBK + s * 8];
            }
#pragma unroll
            for (int nt = 0; nt < NT; nt++) {
                int n = wn + nt * 16 + lo;
                int s = (s2 * 4 + quad + n) & 7;
                bfr[nt] = *(const bf16x8*)&Blds[n * TBK + s * 8];
            }
#pragma unroll
            for (int mt = 0; mt < MT; mt++)
#pragma unroll
                for (int nt = 0; nt < NT; nt++)
                    acc[mt][nt] = __builtin_amdgcn_mfma_f32_16x16x32_bf16(af[mt], bfr[nt], acc[mt][nt], 0, 0, 0);
        }
    }

    // epilogue: D[row=quad*4+i][col=lo] per 16x16 tile
    if (EPI == 0) {
        u16* C = (u16*)Cp + (size_t)blockIdx.z * Ssz;
#pragma unroll
        for (int mt = 0; mt < MT; mt++) {
            int rb = m0 + wm + mt * 16 + quad * 4;
#pragma unroll
            for (int i = 0; i < 4; i++)
#pragma unroll
                for (int nt = 0; nt < NT; nt++)
                    C[(size_t)(rb + i) * ldc + n0 + wn + nt * 16 + lo] = f2b(acc[mt][nt][i]);
        }
    } else {
        u16* C = (u16*)Cp;
        float dv[NT];
#pragma unroll
        for (int nt = 0; nt < NT; nt++) dv[nt] = degv[n0 + wn + nt * 16 + lo];
#pragma unroll
        for (int mt = 0; mt < MT; mt++) {
            int rb = m0 + wm + mt * 16 + quad * 4;
#pragma unroll
            for (int i = 0; i < 4; i++)
#pragma unroll
                for (int nt = 0; nt < NT; nt++)
                    C[(size_t)(rb + i) * ldc + n0 + wn + nt * 16 + lo] =
                        f2b(acc[mt][nt][i] * dv[nt]);
        }
    }
}

// ---------------- launch ----------------

extern "C" void kernel_launch(void* const* d_in, const int* in_sizes, int n_in,
                              void* d_out, int out_size, void* d_ws, size_t ws_size,
                              hipStream_t stream) {
    const float* x    = (const float*)d_in[0];
    const float* H    = (const float*)d_in[1];
    const float* W    = (const float*)d_in[2];
    const float* V    = (const float*)d_in[3];
    const float* bias = (const float*)d_in[4];
    float* out  = (float*)d_out;                       // (N, FT)
    float* wout = out + (size_t)N_NODES * FT;          // (E,)
    (void)in_sizes; (void)n_in; (void)out_size; (void)ws_size;

    char* wsb = (char*)d_ws;
    float* wsf   = (float*)d_ws;
    float* xv    = wsf;               // 8192 f
    float* zsum  = wsf + 8192;        // 4096 f  ┐ zeroed together (8192 f)
    float* desum = wsf + 12288;       // 4096 f  ┘
    float* degv  = wsf + 16384;       // 8192 f
    float* wde   = wsf + 24576;       // 4096 f -> 114,688 B
    u16*   Hbf   = (u16*)(wsb + 114688);       // 8192*4128*2 = 67,633,152 -> 67,747,840
    u16*   HTbf  = (u16*)(wsb + 67747840);     // 4096*8224*2 = 67,371,008 -> 135,118,848
    u16*   WT    = (u16*)(wsb + 135118848);    // 0.5 MB                   -> 135,643,136
    u16*   doutT = (u16*)(wsb + 135643136);    // 512*8224*2  =  8,421,376 -> 144,064,512
    u16*   t2T   = (u16*)(wsb + 144064512);    // 512*4128*2  =  4,227,072 -> 148,291,584
    u16*   xb    = (u16*)(wsb + 148291584);    // 8 MB                     -> 156,680,192
    u16*   P     = (u16*)(wsb + 156680192);    // 32 MB                    -> 190,234,624

    // scalar path (zero folded into xv_xb; sigmoid+wt merged)
    xv_xb_kernel<<<N_NODES / 4, 256, 0, stream>>>(x, V, xv, xb, zsum);
    prep_h4_kernel<<<dim3(N_EDGES / 64, N_NODES / 64), 256, 0, stream>>>(
        H, xv, Hbf, HTbf, zsum, desum);
    sigwt_kernel<<<16 + 256, 256, 0, stream>>>(zsum, desum, wout, wde, W, WT);
    degv_kernel<<<N_NODES / 4, 256, 0, stream>>>(Hbf, wout, degv);

    // G1: doutT[f,n] = degv[n] * sum_fi WT[f,fi]*xb[n,fi]  (M=512, N=8192, K=512)
    gemm9<2, 4, 1><<<dim3(FT / 64, N_NODES / 128, 1), 256, 0, stream>>>(
        WT, xb, doutT, degv, FT, FT, FT, LDD, 0);

    // G2: P[z][e][f] = partial sum_n HTbf[e,n]*doutT[f,n]  (M=4096, N=512, K=8192, S=8)
    gemm9<4, 4, 0><<<dim3(N_EDGES / 128, FT / 128, 8), 256, 0, stream>>>(
        HTbf, doutT, P, nullptr, N_NODES / 8, LDHT, LDD, 512, (size_t)N_EDGES * 512);

    // t2T[f,e] = wde[e] * sum_s P
    t2t_kernel<<<dim3(FT / 32, N_EDGES / 32), dim3(32, 8), 0, stream>>>(P, wde, t2T);

    // G3: P[z][n][f] = partial sum_e Hbf[n,e]*t2T[f,e]   (M=8192, N=512, K=4096, S=4)
    gemm9<4, 4, 0><<<dim3(N_NODES / 128, FT / 128, 4), 256, 0, stream>>>(
        Hbf, t2T, P, nullptr, N_EDGES / 4, LDH, LDT, 512, (size_t)N_NODES * 512);

    // out = degv ⊙ (sum_s P) + bias
    final_kernel<<<(N_NODES * FT / 8) / 256, 256, 0, stream>>>(P, degv, bias, out);
}

// Round 9
// 367.779 us; speedup vs baseline: 1.0685x; 1.0685x over previous
//
#include <hip/hip_runtime.h>

// HGNN conv: out = degv ⊙ (H @ ((w*deg_e) ⊙ (H^T @ (degv ⊙ (x@W))))) + bias ; w = sigmoid(H^T (x V))
// N=8192, E=4096, F=512. R20: exact R14 revert (354us best: unpadded, prep_h4, 11 dispatch)
// + ONE delta: XCD-chunked block swizzle in gemm9 (1D launch, bijective remap: virt =
// (bid&7)*(nwg/8) + bid>>3). Groups each k-slice's blocks onto one XCD so B-chunks L2-fit
// and A panels fetch once per XCD (guide T1). R19's padding reverted (it broke 256B store
// granules: WRITE +5MB, prep 81->100us).

#define N_NODES 8192
#define N_EDGES 4096
#define FT 512

typedef short bf16x8 __attribute__((ext_vector_type(8)));
typedef float f32x4 __attribute__((ext_vector_type(4)));
typedef unsigned short u16;
typedef unsigned int u32;

__device__ __forceinline__ u16 f2b(float f) {
    union { float f; u32 u; } v; v.f = f;
    u32 r = v.u + 0x7FFFu + ((v.u >> 16) & 1u);   // RNE
    return (u16)(r >> 16);
}
__device__ __forceinline__ float b2f(u16 h) {
    union { u32 u; float f; } v; v.u = ((u32)h) << 16; return v.f;
}

// ---------------- scalar-path kernels ----------------

__global__ __launch_bounds__(256) void zero_kernel(float* p, int n) {
    int i = blockIdx.x * 256 + threadIdx.x;
    if (i < n) p[i] = 0.f;
}

// xv[n] = x[n,:] . V ; xb = bf16(x)
__global__ __launch_bounds__(256) void xv_xb_kernel(const float* __restrict__ x,
                                                    const float* __restrict__ V,
                                                    float* __restrict__ xv,
                                                    u16* __restrict__ xb) {
    int row = blockIdx.x * 4 + (threadIdx.x >> 6);
    int lane = threadIdx.x & 63;
    const float* xr = x + (size_t)row * FT + lane * 8;
    const float* vr = V + lane * 8;
    float4 a0 = *(const float4*)xr, a1 = *(const float4*)(xr + 4);
    float4 b0 = *(const float4*)vr, b1 = *(const float4*)(vr + 4);
    float acc = a0.x * b0.x + a0.y * b0.y + a0.z * b0.z + a0.w * b0.w +
                a1.x * b1.x + a1.y * b1.y + a1.z * b1.z + a1.w * b1.w;
    u16 tmp[8] = {f2b(a0.x), f2b(a0.y), f2b(a0.z), f2b(a0.w),
                  f2b(a1.x), f2b(a1.y), f2b(a1.z), f2b(a1.w)};
    *(uint4*)(xb + (size_t)row * FT + lane * 8) = *(uint4*)tmp;
#pragma unroll
    for (int off = 32; off; off >>= 1) acc += __shfl_down(acc, off);
    if (lane == 0) xv[row] = acc;
}

// Fused prep (R14 structure, unpadded): Hbf = bf16(H); HTbf = Hbf^T; zsum/desum accumulate.
// Phase 1 LDS-only before barrier; Hbf stores post-barrier.
__global__ __launch_bounds__(256) void prep_h4_kernel(const float* __restrict__ H,
                                                      const float* __restrict__ xv,
                                                      u16* __restrict__ Hbf,
                                                      u16* __restrict__ HTbf,
                                                      float* __restrict__ zsum,
                                                      float* __restrict__ desum) {
    __shared__ u32 Wt[64][33];                    // Wt[n][ew] = packed e-pair (2ew, 2ew+1)
    __shared__ float xvs[64];
    const int t = threadIdx.x;
    const int e0 = blockIdx.x * 64, n0 = blockIdx.y * 64;
    if (t < 64) xvs[t] = xv[n0 + t];
    const int n_ld = t >> 2, seg = t & 3;
    u32 o[8];
    {   // phase 1: load/convert; LDS write only
        const float* src = H + (size_t)(n0 + n_ld) * N_EDGES + e0 + seg * 16;
#pragma unroll
        for (int j = 0; j < 4; j++) {
            float4 h = *(const float4*)(src + j * 4);
            o[2 * j]     = (h.x != 0.f ? 0x3F80u : 0u) | (h.y != 0.f ? 0x3F800000u : 0u);
            o[2 * j + 1] = (h.z != 0.f ? 0x3F80u : 0u) | (h.w != 0.f ? 0x3F800000u : 0u);
        }
#pragma unroll
        for (int j = 0; j < 8; j++) Wt[n_ld][seg * 8 + j] = o[j];
    }
    __syncthreads();
    {   // Hbf stores post-barrier (from regs)
        u16* hdst = Hbf + (size_t)(n0 + n_ld) * N_EDGES + e0 + seg * 16;
        *(uint4*)hdst       = *(uint4*)&o[0];
        *(uint4*)(hdst + 8) = *(uint4*)&o[4];
    }
    {   // phase 2: perm transpose -> HTbf + z/d accumulation
        int e = t >> 2, g = t & 3;
        int ew = e >> 1;
        u32 sel = (e & 1) ? 0x07060302u : 0x05040100u;
        u32 oo[8];
        float z = 0.f, d = 0.f;
#pragma unroll
        for (int j = 0; j < 8; j++) {
            int np = g * 8 + j;
            oo[j] = __builtin_amdgcn_perm(Wt[2 * np + 1][ew], Wt[2 * np][ew], sel);
            z += (oo[j] & 0xFFFFu) ? xvs[2 * np] : 0.f;
            d += (oo[j] & 0xFFFFu) ? 1.f : 0.f;
            z += (oo[j] >> 16) ? xvs[2 * np + 1] : 0.f;
            d += (oo[j] >> 16) ? 1.f : 0.f;
        }
        u32* drow = (u32*)(HTbf + (size_t)(e0 + e) * N_NODES + n0);
        *(uint4*)(drow + g * 8)     = *(uint4*)&oo[0];
        *(uint4*)(drow + g * 8 + 4) = *(uint4*)&oo[4];
        z += __shfl_down(z, 2); z += __shfl_down(z, 1);
        d += __shfl_down(d, 2); d += __shfl_down(d, 1);
        if (g == 0) {
            atomicAdd(zsum + e0 + e, z);
            atomicAdd(desum + e0 + e, d);
        }
    }
}

__global__ __launch_bounds__(256) void sigmoid_kernel(const float* __restrict__ zsum,
                                                      const float* __restrict__ desum,
                                                      float* __restrict__ w_out,
                                                      float* __restrict__ wde) {
    int e = blockIdx.x * 256 + threadIdx.x;
    float z = zsum[e];
    float wv = 1.f / (1.f + expf(-z));
    w_out[e] = wv;
    wde[e] = wv * desum[e];
}

// degv[n] = Hbf[n,:] . w   (one wave per row; coalesced w loads, cndmask adds)
__global__ __launch_bounds__(256) void degv_kernel(const u16* __restrict__ Hbf,
                                                   const float* __restrict__ w,
                                                   float* __restrict__ degv) {
    int row = blockIdx.x * 4 + (threadIdx.x >> 6);
    int lane = threadIdx.x & 63;
    const uint4* hr = (const uint4*)(Hbf + (size_t)row * N_EDGES);
    float acc = 0.f;
#pragma unroll
    for (int i = 0; i < 8; i++) {
        int idx = i * 64 + lane;
        uint4 h = hr[idx];
        const float* w8 = w + idx * 8;
        float4 wa = *(const float4*)w8, wb = *(const float4*)(w8 + 4);
        acc += (h.x & 0xFFFFu) ? wa.x : 0.f;  acc += (h.x >> 16) ? wa.y : 0.f;
        acc += (h.y & 0xFFFFu) ? wa.z : 0.f;  acc += (h.y >> 16) ? wa.w : 0.f;
        acc += (h.z & 0xFFFFu) ? wb.x : 0.f;  acc += (h.z >> 16) ? wb.y : 0.f;
        acc += (h.w & 0xFFFFu) ? wb.z : 0.f;  acc += (h.w >> 16) ? wb.w : 0.f;
    }
#pragma unroll
    for (int off = 32; off; off >>= 1) acc += __shfl_down(acc, off);
    if (lane == 0) degv[row] = acc;
}

// W (FT,FT) fp32 -> WT (FT,FT) bf16 transposed
__global__ void wt_kernel(const float* __restrict__ src, u16* __restrict__ dst) {
    __shared__ float tile[32][33];
    int tx = threadIdx.x, ty = threadIdx.y;
    int c = blockIdx.x * 32 + tx;
    int r0 = blockIdx.y * 32;
#pragma unroll
    for (int i = 0; i < 4; i++)
        tile[ty + i * 8][tx] = src[(size_t)(r0 + ty + i * 8) * FT + c];
    __syncthreads();
#pragma unroll
    for (int i = 0; i < 4; i++)
        dst[(size_t)(blockIdx.x * 32 + ty + i * 8) * FT + r0 + tx] = f2b(tile[tx][ty + i * 8]);
}

// t2T[f,e] = f2b(wde[e] * sum_{s<8} P[s][e][f])
__global__ void t2t_kernel(const u16* __restrict__ P, const float* __restrict__ wde,
                           u16* __restrict__ t2T) {
    __shared__ float tile[32][33];
    int tx = threadIdx.x, ty = threadIdx.y;
    int f0 = blockIdx.x * 32, e0 = blockIdx.y * 32;
#pragma unroll
    for (int i = 0; i < 4; i++) {
        int e = e0 + ty + i * 8;
        size_t idx = (size_t)e * 512 + f0 + tx;
        float s = 0.f;
#pragma unroll
        for (int sl = 0; sl < 8; sl++)
            s += b2f(P[idx + (size_t)sl * N_EDGES * 512]);
        tile[ty + i * 8][tx] = wde[e] * s;
    }
    __syncthreads();
#pragma unroll
    for (int i = 0; i < 4; i++)
        t2T[(size_t)(f0 + ty + i * 8) * N_EDGES + e0 + tx] = f2b(tile[tx][ty + i * 8]);
}

// out[n,f] = degv[n]*sum_{s<4} P[s][n][f] + bias[f]
__global__ __launch_bounds__(256) void final_kernel(const u16* __restrict__ P,
                                                    const float* __restrict__ degv,
                                                    const float* __restrict__ bias,
                                                    float* __restrict__ out) {
    int i8 = blockIdx.x * 256 + threadIdx.x;
    int base = i8 * 8;
    int n = base >> 9, f = base & 511;
    float s[8] = {0.f, 0.f, 0.f, 0.f, 0.f, 0.f, 0.f, 0.f};
#pragma unroll
    for (int sl = 0; sl < 4; sl++) {
        uint4 v = *(const uint4*)(P + (size_t)sl * N_NODES * 512 + base);
        u32 ws[4] = {v.x, v.y, v.z, v.w};
#pragma unroll
        for (int j = 0; j < 4; j++) {
            s[2 * j]     += b2f((u16)(ws[j] & 0xFFFFu));
            s[2 * j + 1] += b2f((u16)(ws[j] >> 16));
        }
    }
    float dv = degv[n];
    float4 o0, o1;
    o0.x = dv * s[0] + bias[f + 0]; o0.y = dv * s[1] + bias[f + 1];
    o0.z = dv * s[2] + bias[f + 2]; o0.w = dv * s[3] + bias[f + 3];
    o1.x = dv * s[4] + bias[f + 4]; o1.y = dv * s[5] + bias[f + 5];
    o1.z = dv * s[6] + bias[f + 6]; o1.w = dv * s[7] + bias[f + 7];
    *(float4*)(out + base) = o0;
    *(float4*)(out + base + 4) = o1;
}

// ---------------- MFMA GEMM: TBK=64, full-DMA + rotate-by-row swizzle ----------------
// Tile (MT*32) x (NT*32), 4 waves (2x2). bf16 row-major operands, k-contiguous.
// 1D grid + XCD-chunked decode: virt = (bid&7)*(nwg/8) + (bid>>3); x fastest, then y, z.
// Groups consecutive virt (shared B-chunk / k-slice) onto one XCD's L2.
// EPI 0: bf16 partial store at Cp + z*Ssz, ldc-row-major
// EPI 1: bf16 store C[m*ldc+n] scaled by degv[n]

#define TBK 64

template <int MT, int NT, int EPI>
__global__ __launch_bounds__(256, 4)
void gemm9(const u16* __restrict__ Ap, const u16* __restrict__ Bp,
           void* __restrict__ Cp, const float* __restrict__ degv,
           int KC, int lda, int ldb, int ldc, size_t Ssz, int gx, int gy) {
    __shared__ __align__(16) u16 Alds[MT * 32 * TBK];
    __shared__ __align__(16) u16 Blds[NT * 32 * TBK];
    const int t = threadIdx.x;
    // XCD-chunked swizzle (bijective: gridDim.x is a multiple of 8)
    const int nwg = gridDim.x;
    const int cpx = nwg >> 3;
    const int bid = blockIdx.x;
    const int virt = (bid & 7) * cpx + (bid >> 3);
    const int bx = virt % gx;
    const int rem = virt / gx;
    const int by = rem % gy;
    const int bz = rem / gy;

    const int m0 = bx * (MT * 32), n0 = by * (NT * 32);
    const int kbase = bz * KC;
    const int wave = t >> 6, lane = t & 63, quad = lane >> 4, lo = lane & 15;
    const int wm = (wave >> 1) * (MT * 16), wn = (wave & 1) * (NT * 16);

    f32x4 acc[MT][NT];
#pragma unroll
    for (int a = 0; a < MT; a++)
#pragma unroll
        for (int b = 0; b < NT; b++) acc[a][b] = (f32x4){0.f, 0.f, 0.f, 0.f};

    for (int kk = 0; kk < KC; kk += TBK) {
        const int k0 = kbase + kk;
        __syncthreads();
#pragma unroll
        for (int i = 0; i < MT; i++) {            // A: MT*32 rows x 8 chunks
            int c = t + i * 256;
            int r = c >> 3;
            int j = ((c & 7) - r) & 7;
            const u16* g = Ap + (size_t)(m0 + r) * lda + k0 + j * 8;
            __builtin_amdgcn_global_load_lds((const u32*)g, (u32*)(Alds + c * 8), 16, 0, 0);
        }
#pragma unroll
        for (int i = 0; i < NT; i++) {            // B: NT*32 rows x 8 chunks
            int c = t + i * 256;
            int r = c >> 3;
            int j = ((c & 7) - r) & 7;
            const u16* g = Bp + (size_t)(n0 + r) * ldb + k0 + j * 8;
            __builtin_amdgcn_global_load_lds((const u32*)g, (u32*)(Blds + c * 8), 16, 0, 0);
        }
        __syncthreads();

#pragma unroll
        for (int s2 = 0; s2 < 2; s2++) {
            bf16x8 af[MT], bfr[NT];
#pragma unroll
            for (int mt = 0; mt < MT; mt++) {
                int m = wm + mt * 16 + lo;
                int s = (s2 * 4 + quad + m) & 7;
                af[mt] = *(const bf16x8*)&Alds[m * TBK + s * 8];
            }
#pragma unroll
            for (int nt = 0; nt < NT; nt++) {
                int n = wn + nt * 16 + lo;
                int s = (s2 * 4 + quad + n) & 7;
                bfr[nt] = *(const bf16x8*)&Blds[n * TBK + s * 8];
            }
#pragma unroll
            for (int mt = 0; mt < MT; mt++)
#pragma unroll
                for (int nt = 0; nt < NT; nt++)
                    acc[mt][nt] = __builtin_amdgcn_mfma_f32_16x16x32_bf16(af[mt], bfr[nt], acc[mt][nt], 0, 0, 0);
        }
    }

    // epilogue: D[row=quad*4+i][col=lo] per 16x16 tile
    if (EPI == 0) {
        u16* C = (u16*)Cp + (size_t)bz * Ssz;
#pragma unroll
        for (int mt = 0; mt < MT; mt++) {
            int rb = m0 + wm + mt * 16 + quad * 4;
#pragma unroll
            for (int i = 0; i < 4; i++)
#pragma unroll
                for (int nt = 0; nt < NT; nt++)
                    C[(size_t)(rb + i) * ldc + n0 + wn + nt * 16 + lo] = f2b(acc[mt][nt][i]);
        }
    } else {
        u16* C = (u16*)Cp;
        float dv[NT];
#pragma unroll
        for (int nt = 0; nt < NT; nt++) dv[nt] = degv[n0 + wn + nt * 16 + lo];
#pragma unroll
        for (int mt = 0; mt < MT; mt++) {
            int rb = m0 + wm + mt * 16 + quad * 4;
#pragma unroll
            for (int i = 0; i < 4; i++)
#pragma unroll
                for (int nt = 0; nt < NT; nt++)
                    C[(size_t)(rb + i) * ldc + n0 + wn + nt * 16 + lo] =
                        f2b(acc[mt][nt][i] * dv[nt]);
        }
    }
}

// ---------------- launch ----------------

extern "C" void kernel_launch(void* const* d_in, const int* in_sizes, int n_in,
                              void* d_out, int out_size, void* d_ws, size_t ws_size,
                              hipStream_t stream) {
    const float* x    = (const float*)d_in[0];
    const float* H    = (const float*)d_in[1];
    const float* W    = (const float*)d_in[2];
    const float* V    = (const float*)d_in[3];
    const float* bias = (const float*)d_in[4];
    float* out  = (float*)d_out;                       // (N, FT)
    float* wout = out + (size_t)N_NODES * FT;          // (E,)
    (void)in_sizes; (void)n_in; (void)out_size; (void)ws_size;

    char* wsb = (char*)d_ws;
    float* wsf   = (float*)d_ws;
    float* xv    = wsf;               // 8192 f
    float* zsum  = wsf + 8192;        // 4096 f  ┐ zeroed together (8192 f)
    float* desum = wsf + 12288;       // 4096 f  ┘
    float* degv  = wsf + 16384;       // 8192 f  (written directly)
    float* wde   = wsf + 24576;       // 4096 f -> 114,688 B
    u16*   Hbf   = (u16*)(wsb + 114688);                 // 64 MB  -> 67,223,552
    u16*   HTbf  = (u16*)(wsb + 67223552);               // 64 MB  -> 134,332,416
    u16*   WT    = (u16*)(wsb + 134332416);              // 0.5 MB -> 134,856,704
    u16*   doutT = (u16*)(wsb + 134856704);              // 8 MB   -> 143,245,312
    u16*   t2T   = (u16*)(wsb + 143245312);              // 4 MB   -> 147,439,616
    u16*   xb    = (u16*)(wsb + 147439616);              // 8 MB   -> 155,828,224
    u16*   P     = (u16*)(wsb + 155828224);              // 32 MB  -> 189,382,656

    // scalar path
    zero_kernel<<<32, 256, 0, stream>>>(zsum, 8192);     // zsum + desum
    xv_xb_kernel<<<N_NODES / 4, 256, 0, stream>>>(x, V, xv, xb);
    prep_h4_kernel<<<dim3(N_EDGES / 64, N_NODES / 64), 256, 0, stream>>>(
        H, xv, Hbf, HTbf, zsum, desum);
    sigmoid_kernel<<<N_EDGES / 256, 256, 0, stream>>>(zsum, desum, wout, wde);
    degv_kernel<<<N_NODES / 4, 256, 0, stream>>>(Hbf, wout, degv);
    wt_kernel<<<dim3(16, 16), dim3(32, 8), 0, stream>>>(W, WT);

    // G1: doutT[f,n] = degv[n] * sum_fi WT[f,fi]*xb[n,fi]  (M=512, N=8192, K=512)
    // grid (gx=8 m-blocks, gy=64 n-blocks, gz=1) = 512 blocks
    gemm9<2, 4, 1><<<512, 256, 0, stream>>>(
        WT, xb, doutT, degv, FT, FT, FT, N_NODES, 0, 8, 64);

    // G2: P[z][e][f] = partial sum_n HTbf[e,n]*doutT[f,n]  (M=4096, N=512, K=8192, S=8)
    // grid (gx=32 e-blocks, gy=4 f-blocks, gz=8) = 1024 blocks
    gemm9<4, 4, 0><<<1024, 256, 0, stream>>>(
        HTbf, doutT, P, nullptr, N_NODES / 8, N_NODES, N_NODES, 512,
        (size_t)N_EDGES * 512, 32, 4);

    // t2T[f,e] = wde[e] * sum_s P
    t2t_kernel<<<dim3(FT / 32, N_EDGES / 32), dim3(32, 8), 0, stream>>>(P, wde, t2T);

    // G3: P[z][n][f] = partial sum_e Hbf[n,e]*t2T[f,e]   (M=8192, N=512, K=4096, S=4)
    // grid (gx=64 n-blocks, gy=4 f-blocks, gz=4) = 1024 blocks
    gemm9<4, 4, 0><<<1024, 256, 0, stream>>>(
        Hbf, t2T, P, nullptr, N_EDGES / 4, N_EDGES, N_EDGES, 512,
        (size_t)N_NODES * 512, 64, 4);

    // out = degv ⊙ (sum_s P) + bias
    final_kernel<<<(N_NODES * FT / 8) / 256, 256, 0, stream>>>(P, degv, bias, out);
}

// Round 11
// 362.393 us; speedup vs baseline: 1.0843x; 1.0149x over previous
//
#include <hip/hip_runtime.h>

// HGNN conv: out = degv ⊙ (H @ ((w*deg_e) ⊙ (H^T @ (degv ⊙ (x@W))))) + bias ; w = sigmoid(H^T (x V))
// N=8192, E=4096, F=512. R21b: resubmit of R21 (prior bench failed on container infra, not
// kernel). R14 compute cores (354us best) + dispatch fusion 11->8. Merges: (1) xvwt =
// xv_xb + zero-fold + W-transpose (R15-verified branches); (2) degvw = degv with inline
// sigmoid (identical f32 math) + wout/wde prelude blocks. prep_h4 / G1 / G2 / t2t / G3 /
// final byte-identical to R14.

#define N_NODES 8192
#define N_EDGES 4096
#define FT 512

typedef short bf16x8 __attribute__((ext_vector_type(8)));
typedef float f32x4 __attribute__((ext_vector_type(4)));
typedef unsigned short u16;
typedef unsigned int u32;

__device__ __forceinline__ u16 f2b(float f) {
    union { float f; u32 u; } v; v.f = f;
    u32 r = v.u + 0x7FFFu + ((v.u >> 16) & 1u);   // RNE
    return (u16)(r >> 16);
}
__device__ __forceinline__ float b2f(u16 h) {
    union { u32 u; float f; } v; v.u = ((u32)h) << 16; return v.f;
}

// ---------------- scalar-path kernels ----------------

// blocks 0..2047: xv[n] = x[n,:].V ; xb = bf16(x); blocks 0..31 also zero zsum+desum.
// blocks 2048..2303: W (FT,FT) fp32 -> WT bf16 transposed (flat-index wt, R15-verified).
__global__ __launch_bounds__(256) void xvwt_kernel(const float* __restrict__ x,
                                                   const float* __restrict__ V,
                                                   float* __restrict__ xv,
                                                   u16* __restrict__ xb,
                                                   float* __restrict__ zd,
                                                   const float* __restrict__ W,
                                                   u16* __restrict__ WT) {
    __shared__ float tile[32][33];
    const int bx = blockIdx.x;
    if (bx >= 2048) {                             // W transpose branch
        int b = bx - 2048;
        int bxx = b & 15, byy = b >> 4;
        int tx = threadIdx.x & 31, ty = threadIdx.x >> 5;
        int c = bxx * 32 + tx;
        int r0 = byy * 32;
#pragma unroll
        for (int i = 0; i < 4; i++)
            tile[ty + i * 8][tx] = W[(size_t)(r0 + ty + i * 8) * FT + c];
        __syncthreads();
#pragma unroll
        for (int i = 0; i < 4; i++)
            WT[(size_t)(bxx * 32 + ty + i * 8) * FT + r0 + tx] = f2b(tile[tx][ty + i * 8]);
        return;
    }
    if (bx < 32) zd[bx * 256 + threadIdx.x] = 0.f;
    int row = bx * 4 + (threadIdx.x >> 6);
    int lane = threadIdx.x & 63;
    const float* xr = x + (size_t)row * FT + lane * 8;
    const float* vr = V + lane * 8;
    float4 a0 = *(const float4*)xr, a1 = *(const float4*)(xr + 4);
    float4 b0 = *(const float4*)vr, b1 = *(const float4*)(vr + 4);
    float acc = a0.x * b0.x + a0.y * b0.y + a0.z * b0.z + a0.w * b0.w +
                a1.x * b1.x + a1.y * b1.y + a1.z * b1.z + a1.w * b1.w;
    u16 tmp[8] = {f2b(a0.x), f2b(a0.y), f2b(a0.z), f2b(a0.w),
                  f2b(a1.x), f2b(a1.y), f2b(a1.z), f2b(a1.w)};
    *(uint4*)(xb + (size_t)row * FT + lane * 8) = *(uint4*)tmp;
#pragma unroll
    for (int off = 32; off; off >>= 1) acc += __shfl_down(acc, off);
    if (lane == 0) xv[row] = acc;
}

// Fused prep (R14, unpadded): Hbf = bf16(H); HTbf = Hbf^T; zsum/desum accumulate.
__global__ __launch_bounds__(256) void prep_h4_kernel(const float* __restrict__ H,
                                                      const float* __restrict__ xv,
                                                      u16* __restrict__ Hbf,
                                                      u16* __restrict__ HTbf,
                                                      float* __restrict__ zsum,
                                                      float* __restrict__ desum) {
    __shared__ u32 Wt[64][33];                    // Wt[n][ew] = packed e-pair (2ew, 2ew+1)
    __shared__ float xvs[64];
    const int t = threadIdx.x;
    const int e0 = blockIdx.x * 64, n0 = blockIdx.y * 64;
    if (t < 64) xvs[t] = xv[n0 + t];
    const int n_ld = t >> 2, seg = t & 3;
    u32 o[8];
    {   // phase 1: load/convert; LDS write only
        const float* src = H + (size_t)(n0 + n_ld) * N_EDGES + e0 + seg * 16;
#pragma unroll
        for (int j = 0; j < 4; j++) {
            float4 h = *(const float4*)(src + j * 4);
            o[2 * j]     = (h.x != 0.f ? 0x3F80u : 0u) | (h.y != 0.f ? 0x3F800000u : 0u);
            o[2 * j + 1] = (h.z != 0.f ? 0x3F80u : 0u) | (h.w != 0.f ? 0x3F800000u : 0u);
        }
#pragma unroll
        for (int j = 0; j < 8; j++) Wt[n_ld][seg * 8 + j] = o[j];
    }
    __syncthreads();
    {   // Hbf stores post-barrier (from regs)
        u16* hdst = Hbf + (size_t)(n0 + n_ld) * N_EDGES + e0 + seg * 16;
        *(uint4*)hdst       = *(uint4*)&o[0];
        *(uint4*)(hdst + 8) = *(uint4*)&o[4];
    }
    {   // phase 2: perm transpose -> HTbf + z/d accumulation
        int e = t >> 2, g = t & 3;
        int ew = e >> 1;
        u32 sel = (e & 1) ? 0x07060302u : 0x05040100u;
        u32 oo[8];
        float z = 0.f, d = 0.f;
#pragma unroll
        for (int j = 0; j < 8; j++) {
            int np = g * 8 + j;
            oo[j] = __builtin_amdgcn_perm(Wt[2 * np + 1][ew], Wt[2 * np][ew], sel);
            z += (oo[j] & 0xFFFFu) ? xvs[2 * np] : 0.f;
            d += (oo[j] & 0xFFFFu) ? 1.f : 0.f;
            z += (oo[j] >> 16) ? xvs[2 * np + 1] : 0.f;
            d += (oo[j] >> 16) ? 1.f : 0.f;
        }
        u32* drow = (u32*)(HTbf + (size_t)(e0 + e) * N_NODES + n0);
        *(uint4*)(drow + g * 8)     = *(uint4*)&oo[0];
        *(uint4*)(drow + g * 8 + 4) = *(uint4*)&oo[4];
        z += __shfl_down(z, 2); z += __shfl_down(z, 1);
        d += __shfl_down(d, 2); d += __shfl_down(d, 1);
        if (g == 0) {
            atomicAdd(zsum + e0 + e, z);
            atomicAdd(desum + e0 + e, d);
        }
    }
}

// degv[n] = sum_e Hbf[n,e] * sigmoid(zsum[e])  (sigmoid inlined; identical f32 math).
// Blocks 0..15 also write wout[e] and wde[e] = w*desum[e] as a prelude.
__global__ __launch_bounds__(256) void degvw_kernel(const u16* __restrict__ Hbf,
                                                    const float* __restrict__ zsum,
                                                    const float* __restrict__ desum,
                                                    float* __restrict__ degv,
                                                    float* __restrict__ wout,
                                                    float* __restrict__ wde) {
    const int bx = blockIdx.x;
    if (bx < 16) {
        int e = bx * 256 + threadIdx.x;
        float z = zsum[e];
        float wv = 1.f / (1.f + expf(-z));
        wout[e] = wv;
        wde[e] = wv * desum[e];
    }
    int row = bx * 4 + (threadIdx.x >> 6);
    int lane = threadIdx.x & 63;
    const uint4* hr = (const uint4*)(Hbf + (size_t)row * N_EDGES);
    float acc = 0.f;
#pragma unroll
    for (int i = 0; i < 8; i++) {
        int idx = i * 64 + lane;
        uint4 h = hr[idx];
        const float* z8 = zsum + idx * 8;
        float4 za = *(const float4*)z8, zb = *(const float4*)(z8 + 4);
        float4 wa, wb;
        wa.x = 1.f / (1.f + expf(-za.x)); wa.y = 1.f / (1.f + expf(-za.y));
        wa.z = 1.f / (1.f + expf(-za.z)); wa.w = 1.f / (1.f + expf(-za.w));
        wb.x = 1.f / (1.f + expf(-zb.x)); wb.y = 1.f / (1.f + expf(-zb.y));
        wb.z = 1.f / (1.f + expf(-zb.z)); wb.w = 1.f / (1.f + expf(-zb.w));
        acc += (h.x & 0xFFFFu) ? wa.x : 0.f;  acc += (h.x >> 16) ? wa.y : 0.f;
        acc += (h.y & 0xFFFFu) ? wa.z : 0.f;  acc += (h.y >> 16) ? wa.w : 0.f;
        acc += (h.z & 0xFFFFu) ? wb.x : 0.f;  acc += (h.z >> 16) ? wb.y : 0.f;
        acc += (h.w & 0xFFFFu) ? wb.z : 0.f;  acc += (h.w >> 16) ? wb.w : 0.f;
    }
#pragma unroll
    for (int off = 32; off; off >>= 1) acc += __shfl_down(acc, off);
    if (lane == 0) degv[row] = acc;
}

// t2T[f,e] = f2b(wde[e] * sum_{s<8} P[s][e][f])
__global__ void t2t_kernel(const u16* __restrict__ P, const float* __restrict__ wde,
                           u16* __restrict__ t2T) {
    __shared__ float tile[32][33];
    int tx = threadIdx.x, ty = threadIdx.y;
    int f0 = blockIdx.x * 32, e0 = blockIdx.y * 32;
#pragma unroll
    for (int i = 0; i < 4; i++) {
        int e = e0 + ty + i * 8;
        size_t idx = (size_t)e * 512 + f0 + tx;
        float s = 0.f;
#pragma unroll
        for (int sl = 0; sl < 8; sl++)
            s += b2f(P[idx + (size_t)sl * N_EDGES * 512]);
        tile[ty + i * 8][tx] = wde[e] * s;
    }
    __syncthreads();
#pragma unroll
    for (int i = 0; i < 4; i++)
        t2T[(size_t)(f0 + ty + i * 8) * N_EDGES + e0 + tx] = f2b(tile[tx][ty + i * 8]);
}

// out[n,f] = degv[n]*sum_{s<4} P[s][n][f] + bias[f]
__global__ __launch_bounds__(256) void final_kernel(const u16* __restrict__ P,
                                                    const float* __restrict__ degv,
                                                    const float* __restrict__ bias,
                                                    float* __restrict__ out) {
    int i8 = blockIdx.x * 256 + threadIdx.x;
    int base = i8 * 8;
    int n = base >> 9, f = base & 511;
    float s[8] = {0.f, 0.f, 0.f, 0.f, 0.f, 0.f, 0.f, 0.f};
#pragma unroll
    for (int sl = 0; sl < 4; sl++) {
        uint4 v = *(const uint4*)(P + (size_t)sl * N_NODES * 512 + base);
        u32 ws[4] = {v.x, v.y, v.z, v.w};
#pragma unroll
        for (int j = 0; j < 4; j++) {
            s[2 * j]     += b2f((u16)(ws[j] & 0xFFFFu));
            s[2 * j + 1] += b2f((u16)(ws[j] >> 16));
        }
    }
    float dv = degv[n];
    float4 o0, o1;
    o0.x = dv * s[0] + bias[f + 0]; o0.y = dv * s[1] + bias[f + 1];
    o0.z = dv * s[2] + bias[f + 2]; o0.w = dv * s[3] + bias[f + 3];
    o1.x = dv * s[4] + bias[f + 4]; o1.y = dv * s[5] + bias[f + 5];
    o1.z = dv * s[6] + bias[f + 6]; o1.w = dv * s[7] + bias[f + 7];
    *(float4*)(out + base) = o0;
    *(float4*)(out + base + 4) = o1;
}

// ---------------- MFMA GEMM: TBK=64, full-DMA + rotate-by-row swizzle ----------------
// Tile (MT*32) x (NT*32), 4 waves (2x2). bf16 row-major operands, k-contiguous.
// EPI 0: bf16 partial store at Cp + z*Ssz, ldc-row-major
// EPI 1: bf16 store C[m*ldc+n] scaled by degv[n]

#define TBK 64

template <int MT, int NT, int EPI>
__global__ __launch_bounds__(256, 4)
void gemm9(const u16* __restrict__ Ap, const u16* __restrict__ Bp,
           void* __restrict__ Cp, const float* __restrict__ degv,
           int KC, int lda, int ldb, int ldc, size_t Ssz) {
    __shared__ __align__(16) u16 Alds[MT * 32 * TBK];
    __shared__ __align__(16) u16 Blds[NT * 32 * TBK];
    const int t = threadIdx.x;
    const int m0 = blockIdx.x * (MT * 32), n0 = blockIdx.y * (NT * 32);
    const int kbase = blockIdx.z * KC;
    const int wave = t >> 6, lane = t & 63, quad = lane >> 4, lo = lane & 15;
    const int wm = (wave >> 1) * (MT * 16), wn = (wave & 1) * (NT * 16);

    f32x4 acc[MT][NT];
#pragma unroll
    for (int a = 0; a < MT; a++)
#pragma unroll
        for (int b = 0; b < NT; b++) acc[a][b] = (f32x4){0.f, 0.f, 0.f, 0.f};

    for (int kk = 0; kk < KC; kk += TBK) {
        const int k0 = kbase + kk;
        __syncthreads();
#pragma unroll
        for (int i = 0; i < MT; i++) {            // A: MT*32 rows x 8 chunks
            int c = t + i * 256;
            int r = c >> 3;
            int j = ((c & 7) - r) & 7;
            const u16* g = Ap + (size_t)(m0 + r) * lda + k0 + j * 8;
            __builtin_amdgcn_global_load_lds((const u32*)g, (u32*)(Alds + c * 8), 16, 0, 0);
        }
#pragma unroll
        for (int i = 0; i < NT; i++) {            // B: NT*32 rows x 8 chunks
            int c = t + i * 256;
            int r = c >> 3;
            int j = ((c & 7) - r) & 7;
            const u16* g = Bp + (size_t)(n0 + r) * ldb + k0 + j * 8;
            __builtin_amdgcn_global_load_lds((const u32*)g, (u32*)(Blds + c * 8), 16, 0, 0);
        }
        __syncthreads();

#pragma unroll
        for (int s2 = 0; s2 < 2; s2++) {
            bf16x8 af[MT], bfr[NT];
#pragma unroll
            for (int mt = 0; mt < MT; mt++) {
                int m = wm + mt * 16 + lo;
                int s = (s2 * 4 + quad + m) & 7;
                af[mt] = *(const bf16x8*)&Alds[m * TBK + s * 8];
            }
#pragma unroll
            for (int nt = 0; nt < NT; nt++) {
                int n = wn + nt * 16 + lo;
                int s = (s2 * 4 + quad + n) & 7;
                bfr[nt] = *(const bf16x8*)&Blds[n * TBK + s * 8];
            }
#pragma unroll
            for (int mt = 0; mt < MT; mt++)
#pragma unroll
                for (int nt = 0; nt < NT; nt++)
                    acc[mt][nt] = __builtin_amdgcn_mfma_f32_16x16x32_bf16(af[mt], bfr[nt], acc[mt][nt], 0, 0, 0);
        }
    }

    // epilogue: D[row=quad*4+i][col=lo] per 16x16 tile
    if (EPI == 0) {
        u16* C = (u16*)Cp + (size_t)blockIdx.z * Ssz;
#pragma unroll
        for (int mt = 0; mt < MT; mt++) {
            int rb = m0 + wm + mt * 16 + quad * 4;
#pragma unroll
            for (int i = 0; i < 4; i++)
#pragma unroll
                for (int nt = 0; nt < NT; nt++)
                    C[(size_t)(rb + i) * ldc + n0 + wn + nt * 16 + lo] = f2b(acc[mt][nt][i]);
        }
    } else {
        u16* C = (u16*)Cp;
        float dv[NT];
#pragma unroll
        for (int nt = 0; nt < NT; nt++) dv[nt] = degv[n0 + wn + nt * 16 + lo];
#pragma unroll
        for (int mt = 0; mt < MT; mt++) {
            int rb = m0 + wm + mt * 16 + quad * 4;
#pragma unroll
            for (int i = 0; i < 4; i++)
#pragma unroll
                for (int nt = 0; nt < NT; nt++)
                    C[(size_t)(rb + i) * ldc + n0 + wn + nt * 16 + lo] =
                        f2b(acc[mt][nt][i] * dv[nt]);
        }
    }
}

// ---------------- launch ----------------

extern "C" void kernel_launch(void* const* d_in, const int* in_sizes, int n_in,
                              void* d_out, int out_size, void* d_ws, size_t ws_size,
                              hipStream_t stream) {
    const float* x    = (const float*)d_in[0];
    const float* H    = (const float*)d_in[1];
    const float* W    = (const float*)d_in[2];
    const float* V    = (const float*)d_in[3];
    const float* bias = (const float*)d_in[4];
    float* out  = (float*)d_out;                       // (N, FT)
    float* wout = out + (size_t)N_NODES * FT;          // (E,)
    (void)in_sizes; (void)n_in; (void)out_size; (void)ws_size;

    char* wsb = (char*)d_ws;
    float* wsf   = (float*)d_ws;
    float* xv    = wsf;               // 8192 f
    float* zsum  = wsf + 8192;        // 4096 f  ┐ zeroed together (8192 f)
    float* desum = wsf + 12288;       // 4096 f  ┘
    float* degv  = wsf + 16384;       // 8192 f  (written directly)
    float* wde   = wsf + 24576;       // 4096 f -> 114,688 B
    u16*   Hbf   = (u16*)(wsb + 114688);                 // 64 MB  -> 67,223,552
    u16*   HTbf  = (u16*)(wsb + 67223552);               // 64 MB  -> 134,332,416
    u16*   WT    = (u16*)(wsb + 134332416);              // 0.5 MB -> 134,856,704
    u16*   doutT = (u16*)(wsb + 134856704);              // 8 MB   -> 143,245,312
    u16*   t2T   = (u16*)(wsb + 143245312);              // 4 MB   -> 147,439,616
    u16*   xb    = (u16*)(wsb + 147439616);              // 8 MB   -> 155,828,224
    u16*   P     = (u16*)(wsb + 155828224);              // 32 MB  -> 189,382,656

    // fused scalar path: xv+xb+zero (blocks 0..2047) and W->WT (blocks 2048..2303)
    xvwt_kernel<<<2048 + 256, 256, 0, stream>>>(x, V, xv, xb, zsum, W, WT);
    prep_h4_kernel<<<dim3(N_EDGES / 64, N_NODES / 64), 256, 0, stream>>>(
        H, xv, Hbf, HTbf, zsum, desum);
    // degv with inline sigmoid; blocks 0..15 write wout + wde
    degvw_kernel<<<N_NODES / 4, 256, 0, stream>>>(Hbf, zsum, desum, degv, wout, wde);

    // G1: doutT[f,n] = degv[n] * sum_fi WT[f,fi]*xb[n,fi]  (M=512, N=8192, K=512)
    gemm9<2, 4, 1><<<dim3(FT / 64, N_NODES / 128, 1), 256, 0, stream>>>(
        WT, xb, doutT, degv, FT, FT, FT, N_NODES, 0);

    // G2: P[z][e][f] = partial sum_n HTbf[e,n]*doutT[f,n]  (M=4096, N=512, K=8192, S=8)
    gemm9<4, 4, 0><<<dim3(N_EDGES / 128, FT / 128, 8), 256, 0, stream>>>(
        HTbf, doutT, P, nullptr, N_NODES / 8, N_NODES, N_NODES, 512, (size_t)N_EDGES * 512);

    // t2T[f,e] = wde[e] * sum_s P
    t2t_kernel<<<dim3(FT / 32, N_EDGES / 32), dim3(32, 8), 0, stream>>>(P, wde, t2T);

    // G3: P[z][n][f] = partial sum_e Hbf[n,e]*t2T[f,e]   (M=8192, N=512, K=4096, S=4)
    gemm9<4, 4, 0><<<dim3(N_NODES / 128, FT / 128, 4), 256, 0, stream>>>(
        Hbf, t2T, P, nullptr, N_EDGES / 4, N_EDGES, N_EDGES, 512, (size_t)N_NODES * 512);

    // out = degv ⊙ (sum_s P) + bias
    final_kernel<<<(N_NODES * FT / 8) / 256, 256, 0, stream>>>(P, degv, bias, out);
}

// Round 12
// 355.186 us; speedup vs baseline: 1.1063x; 1.0203x over previous
//
#include <hip/hip_runtime.h>

// HGNN conv: out = degv ⊙ (H @ ((w*deg_e) ⊙ (H^T @ (degv ⊙ (x@W))))) + bias ; w = sigmoid(H^T (x V))
// N=8192, E=4096, F=512. R22: BIT-PACKED H. H is binary -> Hbf/HTbf (64MB bf16 each)
// replaced by Hmask/HTmask (4MB u64 bitmasks). prep writes drop 135->12MB; degv reads
// 64->4MB; G2/G3 A-operands become L2-resident, expanded in-kernel to the IDENTICAL
// rotate-swizzled LDS layout (bit -> {0,1.0f} bf16 is exact; numerics == R14).
// All other kernels + 11-dispatch arrangement = R14 verbatim (354us best).

#define N_NODES 8192
#define N_EDGES 4096
#define FT 512

typedef short bf16x8 __attribute__((ext_vector_type(8)));
typedef float f32x4 __attribute__((ext_vector_type(4)));
typedef unsigned short u16;
typedef unsigned int u32;
typedef unsigned long long u64;

__device__ __forceinline__ u16 f2b(float f) {
    union { float f; u32 u; } v; v.f = f;
    u32 r = v.u + 0x7FFFu + ((v.u >> 16) & 1u);   // RNE
    return (u16)(r >> 16);
}
__device__ __forceinline__ float b2f(u16 h) {
    union { u32 u; float f; } v; v.u = ((u32)h) << 16; return v.f;
}

// ---------------- scalar-path kernels ----------------

__global__ __launch_bounds__(256) void zero_kernel(float* p, int n) {
    int i = blockIdx.x * 256 + threadIdx.x;
    if (i < n) p[i] = 0.f;
}

// xv[n] = x[n,:] . V ; xb = bf16(x)
__global__ __launch_bounds__(256) void xv_xb_kernel(const float* __restrict__ x,
                                                    const float* __restrict__ V,
                                                    float* __restrict__ xv,
                                                    u16* __restrict__ xb) {
    int row = blockIdx.x * 4 + (threadIdx.x >> 6);
    int lane = threadIdx.x & 63;
    const float* xr = x + (size_t)row * FT + lane * 8;
    const float* vr = V + lane * 8;
    float4 a0 = *(const float4*)xr, a1 = *(const float4*)(xr + 4);
    float4 b0 = *(const float4*)vr, b1 = *(const float4*)(vr + 4);
    float acc = a0.x * b0.x + a0.y * b0.y + a0.z * b0.z + a0.w * b0.w +
                a1.x * b1.x + a1.y * b1.y + a1.z * b1.z + a1.w * b1.w;
    u16 tmp[8] = {f2b(a0.x), f2b(a0.y), f2b(a0.z), f2b(a0.w),
                  f2b(a1.x), f2b(a1.y), f2b(a1.z), f2b(a1.w)};
    *(uint4*)(xb + (size_t)row * FT + lane * 8) = *(uint4*)tmp;
#pragma unroll
    for (int off = 32; off; off >>= 1) acc += __shfl_down(acc, off);
    if (lane == 0) xv[row] = acc;
}

// Bit-packing prep (R14 tile/perm structure): Hmask = bits(H); HTmask = bits(H^T);
// zsum[e] += sum_n H[n,e]*xv[n]; desum[e] += colsum. One u64 store per 4-lane group.
__global__ __launch_bounds__(256) void prep_b_kernel(const float* __restrict__ H,
                                                     const float* __restrict__ xv,
                                                     u64* __restrict__ Hmask,
                                                     u64* __restrict__ HTmask,
                                                     float* __restrict__ zsum,
                                                     float* __restrict__ desum) {
    __shared__ u32 Wt[64][33];                    // Wt[n][ew] = packed e-pair (2ew, 2ew+1)
    __shared__ float xvs[64];
    const int t = threadIdx.x;
    const int e0 = blockIdx.x * 64, n0 = blockIdx.y * 64;
    if (t < 64) xvs[t] = xv[n0 + t];
    const int n_ld = t >> 2, seg = t & 3;
    {   // phase 1: load/convert; LDS write + row bitmask (bit j of m <-> e-off seg*16+j)
        const float* src = H + (size_t)(n0 + n_ld) * N_EDGES + e0 + seg * 16;
        u32 m = 0;
        u32 o[8];
#pragma unroll
        for (int j = 0; j < 4; j++) {
            float4 h = *(const float4*)(src + j * 4);
            o[2 * j]     = (h.x != 0.f ? 0x3F80u : 0u) | (h.y != 0.f ? 0x3F800000u : 0u);
            o[2 * j + 1] = (h.z != 0.f ? 0x3F80u : 0u) | (h.w != 0.f ? 0x3F800000u : 0u);
            m |= (h.x != 0.f ? 1u : 0u) << (4 * j);
            m |= (h.y != 0.f ? 1u : 0u) << (4 * j + 1);
            m |= (h.z != 0.f ? 1u : 0u) << (4 * j + 2);
            m |= (h.w != 0.f ? 1u : 0u) << (4 * j + 3);
        }
#pragma unroll
        for (int j = 0; j < 8; j++) Wt[n_ld][seg * 8 + j] = o[j];
        u32 mlo = m | (__shfl_down(m, 1) << 16);          // seg0|seg1 (valid at seg==0)
        u32 mhi = __shfl_down(mlo, 2);                    // seg2|seg3
        if (seg == 0)
            Hmask[(size_t)(n0 + n_ld) * 64 + (e0 >> 6)] = (u64)mlo | ((u64)mhi << 32);
    }
    __syncthreads();
    {   // phase 2: perm transpose bits -> HTmask + z/d accumulation
        int e = t >> 2, g = t & 3;
        int ew = e >> 1;
        u32 sel = (e & 1) ? 0x07060302u : 0x05040100u;
        float z = 0.f, d = 0.f;
        u32 m2 = 0;                                       // bit k <-> n-off g*16+k
#pragma unroll
        for (int j = 0; j < 8; j++) {
            int np = g * 8 + j;
            u32 v = __builtin_amdgcn_perm(Wt[2 * np + 1][ew], Wt[2 * np][ew], sel);
            z += (v & 0xFFFFu) ? xvs[2 * np] : 0.f;
            d += (v & 0xFFFFu) ? 1.f : 0.f;
            z += (v >> 16) ? xvs[2 * np + 1] : 0.f;
            d += (v >> 16) ? 1.f : 0.f;
            m2 |= ((v & 0xFFFFu) ? 1u : 0u) << (2 * j);
            m2 |= ((v >> 16) ? 1u : 0u) << (2 * j + 1);
        }
        u32 mlo = m2 | (__shfl_down(m2, 1) << 16);        // g0|g1 (valid at g==0)
        u32 mhi = __shfl_down(mlo, 2);                    // g2|g3
        if (g == 0)
            HTmask[(size_t)(e0 + e) * 128 + (n0 >> 6)] = (u64)mlo | ((u64)mhi << 32);
        z += __shfl_down(z, 2); z += __shfl_down(z, 1);
        d += __shfl_down(d, 2); d += __shfl_down(d, 1);
        if (g == 0) {
            atomicAdd(zsum + e0 + e, z);
            atomicAdd(desum + e0 + e, d);
        }
    }
}

__global__ __launch_bounds__(256) void sigmoid_kernel(const float* __restrict__ zsum,
                                                      const float* __restrict__ desum,
                                                      float* __restrict__ w_out,
                                                      float* __restrict__ wde) {
    int e = blockIdx.x * 256 + threadIdx.x;
    float z = zsum[e];
    float wv = 1.f / (1.f + expf(-z));
    w_out[e] = wv;
    wde[e] = wv * desum[e];
}

// degv[n] = sum_e bit(Hmask[n],e) * w[e]. One wave per row; u64/lane; w L1-resident.
__global__ __launch_bounds__(256) void degvm_kernel(const u64* __restrict__ Hmask,
                                                    const float* __restrict__ w,
                                                    float* __restrict__ degv) {
    int row = blockIdx.x * 4 + (threadIdx.x >> 6);
    int lane = threadIdx.x & 63;
    u64 M = Hmask[(size_t)row * 64 + lane];
    const float* wl = w + lane * 64;
    float acc = 0.f;
#pragma unroll
    for (int jj = 0; jj < 16; jj++) {
        float4 wv = *(const float4*)(wl + jj * 4);
        acc += ((M >> (4 * jj)) & 1ull) ? wv.x : 0.f;
        acc += ((M >> (4 * jj + 1)) & 1ull) ? wv.y : 0.f;
        acc += ((M >> (4 * jj + 2)) & 1ull) ? wv.z : 0.f;
        acc += ((M >> (4 * jj + 3)) & 1ull) ? wv.w : 0.f;
    }
#pragma unroll
    for (int off = 32; off; off >>= 1) acc += __shfl_down(acc, off);
    if (lane == 0) degv[row] = acc;
}

// W (FT,FT) fp32 -> WT (FT,FT) bf16 transposed
__global__ void wt_kernel(const float* __restrict__ src, u16* __restrict__ dst) {
    __shared__ float tile[32][33];
    int tx = threadIdx.x, ty = threadIdx.y;
    int c = blockIdx.x * 32 + tx;
    int r0 = blockIdx.y * 32;
#pragma unroll
    for (int i = 0; i < 4; i++)
        tile[ty + i * 8][tx] = src[(size_t)(r0 + ty + i * 8) * FT + c];
    __syncthreads();
#pragma unroll
    for (int i = 0; i < 4; i++)
        dst[(size_t)(blockIdx.x * 32 + ty + i * 8) * FT + r0 + tx] = f2b(tile[tx][ty + i * 8]);
}

// t2T[f,e] = f2b(wde[e] * sum_{s<8} P[s][e][f])
__global__ void t2t_kernel(const u16* __restrict__ P, const float* __restrict__ wde,
                           u16* __restrict__ t2T) {
    __shared__ float tile[32][33];
    int tx = threadIdx.x, ty = threadIdx.y;
    int f0 = blockIdx.x * 32, e0 = blockIdx.y * 32;
#pragma unroll
    for (int i = 0; i < 4; i++) {
        int e = e0 + ty + i * 8;
        size_t idx = (size_t)e * 512 + f0 + tx;
        float s = 0.f;
#pragma unroll
        for (int sl = 0; sl < 8; sl++)
            s += b2f(P[idx + (size_t)sl * N_EDGES * 512]);
        tile[ty + i * 8][tx] = wde[e] * s;
    }
    __syncthreads();
#pragma unroll
    for (int i = 0; i < 4; i++)
        t2T[(size_t)(f0 + ty + i * 8) * N_EDGES + e0 + tx] = f2b(tile[tx][ty + i * 8]);
}

// out[n,f] = degv[n]*sum_{s<4} P[s][n][f] + bias[f]
__global__ __launch_bounds__(256) void final_kernel(const u16* __restrict__ P,
                                                    const float* __restrict__ degv,
                                                    const float* __restrict__ bias,
                                                    float* __restrict__ out) {
    int i8 = blockIdx.x * 256 + threadIdx.x;
    int base = i8 * 8;
    int n = base >> 9, f = base & 511;
    float s[8] = {0.f, 0.f, 0.f, 0.f, 0.f, 0.f, 0.f, 0.f};
#pragma unroll
    for (int sl = 0; sl < 4; sl++) {
        uint4 v = *(const uint4*)(P + (size_t)sl * N_NODES * 512 + base);
        u32 ws[4] = {v.x, v.y, v.z, v.w};
#pragma unroll
        for (int j = 0; j < 4; j++) {
            s[2 * j]     += b2f((u16)(ws[j] & 0xFFFFu));
            s[2 * j + 1] += b2f((u16)(ws[j] >> 16));
        }
    }
    float dv = degv[n];
    float4 o0, o1;
    o0.x = dv * s[0] + bias[f + 0]; o0.y = dv * s[1] + bias[f + 1];
    o0.z = dv * s[2] + bias[f + 2]; o0.w = dv * s[3] + bias[f + 3];
    o1.x = dv * s[4] + bias[f + 4]; o1.y = dv * s[5] + bias[f + 5];
    o1.z = dv * s[6] + bias[f + 6]; o1.w = dv * s[7] + bias[f + 7];
    *(float4*)(out + base) = o0;
    *(float4*)(out + base + 4) = o1;
}

// ---------------- MFMA GEMM: TBK=64, rotate-by-row swizzle ----------------
// Tile (MT*32) x (NT*32), 4 waves (2x2). B: bf16 row-major k-contiguous via DMA.
// A: if AM, bit-packed u64 rows (ldam in u64 units) expanded in-kernel to the SAME
// rotated LDS layout (bit -> {0, 1.0bf16}); else bf16 DMA path (lda in u16 units).
// EPI 0: bf16 partial store at Cp + z*Ssz; EPI 1: bf16 store scaled by degv[n].

#define TBK 64

template <int MT, int NT, int EPI, bool AM>
__global__ __launch_bounds__(256, 4)
void gemm9(const u16* __restrict__ Ap, const u64* __restrict__ Am,
           const u16* __restrict__ Bp, void* __restrict__ Cp,
           const float* __restrict__ degv,
           int KC, int lda, int ldam, int ldb, int ldc, size_t Ssz) {
    __shared__ __align__(16) u16 Alds[MT * 32 * TBK];
    __shared__ __align__(16) u16 Blds[NT * 32 * TBK];
    const int t = threadIdx.x;
    const int m0 = blockIdx.x * (MT * 32), n0 = blockIdx.y * (NT * 32);
    const int kbase = blockIdx.z * KC;
    const int wave = t >> 6, lane = t & 63, quad = lane >> 4, lo = lane & 15;
    const int wm = (wave >> 1) * (MT * 16), wn = (wave & 1) * (NT * 16);

    f32x4 acc[MT][NT];
#pragma unroll
    for (int a = 0; a < MT; a++)
#pragma unroll
        for (int b = 0; b < NT; b++) acc[a][b] = (f32x4){0.f, 0.f, 0.f, 0.f};

    for (int kk = 0; kk < KC; kk += TBK) {
        const int k0 = kbase + kk;
        __syncthreads();
        if constexpr (AM) {                       // A: expand bitmask -> LDS (same layout)
#pragma unroll
            for (int i = 0; i < MT; i++) {
                int c = t + i * 256;
                int r = c >> 3;
                int j = ((c & 7) - r) & 7;        // global k-chunk (rotated slot c&7)
                u64 M = Am[(size_t)(m0 + r) * ldam + (k0 >> 6)];
                u32 b = (u32)(M >> (j * 8)) & 0xFFu;
                u32 w4[4];
                w4[0] = (b & 1u   ? 0x3F80u : 0u) | (b & 2u   ? 0x3F800000u : 0u);
                w4[1] = (b & 4u   ? 0x3F80u : 0u) | (b & 8u   ? 0x3F800000u : 0u);
                w4[2] = (b & 16u  ? 0x3F80u : 0u) | (b & 32u  ? 0x3F800000u : 0u);
                w4[3] = (b & 64u  ? 0x3F80u : 0u) | (b & 128u ? 0x3F800000u : 0u);
                *(uint4*)&Alds[c * 8] = *(uint4*)w4;
            }
        } else {
#pragma unroll
            for (int i = 0; i < MT; i++) {        // A: MT*32 rows x 8 chunks via DMA
                int c = t + i * 256;
                int r = c >> 3;
                int j = ((c & 7) - r) & 7;
                const u16* g = Ap + (size_t)(m0 + r) * lda + k0 + j * 8;
                __builtin_amdgcn_global_load_lds((const u32*)g, (u32*)(Alds + c * 8), 16, 0, 0);
            }
        }
#pragma unroll
        for (int i = 0; i < NT; i++) {            // B: NT*32 rows x 8 chunks via DMA
            int c = t + i * 256;
            int r = c >> 3;
            int j = ((c & 7) - r) & 7;
            const u16* g = Bp + (size_t)(n0 + r) * ldb + k0 + j * 8;
            __builtin_amdgcn_global_load_lds((const u32*)g, (u32*)(Blds + c * 8), 16, 0, 0);
        }
        __syncthreads();

#pragma unroll
        for (int s2 = 0; s2 < 2; s2++) {
            bf16x8 af[MT], bfr[NT];
#pragma unroll
            for (int mt = 0; mt < MT; mt++) {
                int m = wm + mt * 16 + lo;
                int s = (s2 * 4 + quad + m) & 7;
                af[mt] = *(const bf16x8*)&Alds[m * TBK + s * 8];
            }
#pragma unroll
            for (int nt = 0; nt < NT; nt++) {
                int n = wn + nt * 16 + lo;
                int s = (s2 * 4 + quad + n) & 7;
                bfr[nt] = *(const bf16x8*)&Blds[n * TBK + s * 8];
            }
#pragma unroll
            for (int mt = 0; mt < MT; mt++)
#pragma unroll
                for (int nt = 0; nt < NT; nt++)
                    acc[mt][nt] = __builtin_amdgcn_mfma_f32_16x16x32_bf16(af[mt], bfr[nt], acc[mt][nt], 0, 0, 0);
        }
    }

    // epilogue: D[row=quad*4+i][col=lo] per 16x16 tile
    if (EPI == 0) {
        u16* C = (u16*)Cp + (size_t)blockIdx.z * Ssz;
#pragma unroll
        for (int mt = 0; mt < MT; mt++) {
            int rb = m0 + wm + mt * 16 + quad * 4;
#pragma unroll
            for (int i = 0; i < 4; i++)
#pragma unroll
                for (int nt = 0; nt < NT; nt++)
                    C[(size_t)(rb + i) * ldc + n0 + wn + nt * 16 + lo] = f2b(acc[mt][nt][i]);
        }
    } else {
        u16* C = (u16*)Cp;
        float dv[NT];
#pragma unroll
        for (int nt = 0; nt < NT; nt++) dv[nt] = degv[n0 + wn + nt * 16 + lo];
#pragma unroll
        for (int mt = 0; mt < MT; mt++) {
            int rb = m0 + wm + mt * 16 + quad * 4;
#pragma unroll
            for (int i = 0; i < 4; i++)
#pragma unroll
                for (int nt = 0; nt < NT; nt++)
                    C[(size_t)(rb + i) * ldc + n0 + wn + nt * 16 + lo] =
                        f2b(acc[mt][nt][i] * dv[nt]);
        }
    }
}

// ---------------- launch ----------------

extern "C" void kernel_launch(void* const* d_in, const int* in_sizes, int n_in,
                              void* d_out, int out_size, void* d_ws, size_t ws_size,
                              hipStream_t stream) {
    const float* x    = (const float*)d_in[0];
    const float* H    = (const float*)d_in[1];
    const float* W    = (const float*)d_in[2];
    const float* V    = (const float*)d_in[3];
    const float* bias = (const float*)d_in[4];
    float* out  = (float*)d_out;                       // (N, FT)
    float* wout = out + (size_t)N_NODES * FT;          // (E,)
    (void)in_sizes; (void)n_in; (void)out_size; (void)ws_size;

    char* wsb = (char*)d_ws;
    float* wsf   = (float*)d_ws;
    float* xv    = wsf;               // 8192 f
    float* zsum  = wsf + 8192;        // 4096 f  ┐ zeroed together (8192 f)
    float* desum = wsf + 12288;       // 4096 f  ┘
    float* degv  = wsf + 16384;       // 8192 f
    float* wde   = wsf + 24576;       // 4096 f -> 114,688 B
    u64*   Hmask  = (u64*)(wsb + 114688);      // 8192*64*8  = 4 MB -> 4,308,992
    u64*   HTmask = (u64*)(wsb + 4308992);     // 4096*128*8 = 4 MB -> 8,503,296
    u16*   WT     = (u16*)(wsb + 8503296);     // 0.5 MB            -> 9,027,584
    u16*   doutT  = (u16*)(wsb + 9027584);     // 8 MB              -> 17,416,192
    u16*   t2T    = (u16*)(wsb + 17416192);    // 4 MB              -> 21,610,496
    u16*   xb     = (u16*)(wsb + 21610496);    // 8 MB              -> 29,999,104
    u16*   P      = (u16*)(wsb + 29999104);    // 32 MB             -> 63,553,536

    // scalar path (R14 arrangement)
    zero_kernel<<<32, 256, 0, stream>>>(zsum, 8192);     // zsum + desum
    xv_xb_kernel<<<N_NODES / 4, 256, 0, stream>>>(x, V, xv, xb);
    prep_b_kernel<<<dim3(N_EDGES / 64, N_NODES / 64), 256, 0, stream>>>(
        H, xv, Hmask, HTmask, zsum, desum);
    sigmoid_kernel<<<N_EDGES / 256, 256, 0, stream>>>(zsum, desum, wout, wde);
    degvm_kernel<<<N_NODES / 4, 256, 0, stream>>>(Hmask, wout, degv);
    wt_kernel<<<dim3(16, 16), dim3(32, 8), 0, stream>>>(W, WT);

    // G1: doutT[f,n] = degv[n] * sum_fi WT[f,fi]*xb[n,fi]  (M=512, N=8192, K=512)
    gemm9<2, 4, 1, false><<<dim3(FT / 64, N_NODES / 128, 1), 256, 0, stream>>>(
        WT, nullptr, xb, doutT, degv, FT, FT, 0, FT, N_NODES, 0);

    // G2: P[z][e][f] = partial sum_n HTmask[e,n]*doutT[f,n]  (M=4096, N=512, K=8192, S=8)
    gemm9<4, 4, 0, true><<<dim3(N_EDGES / 128, FT / 128, 8), 256, 0, stream>>>(
        nullptr, HTmask, doutT, P, nullptr, N_NODES / 8, 0, 128, N_NODES, 512,
        (size_t)N_EDGES * 512);

    // t2T[f,e] = wde[e] * sum_s P
    t2t_kernel<<<dim3(FT / 32, N_EDGES / 32), dim3(32, 8), 0, stream>>>(P, wde, t2T);

    // G3: P[z][n][f] = partial sum_e Hmask[n,e]*t2T[f,e]   (M=8192, N=512, K=4096, S=4)
    gemm9<4, 4, 0, true><<<dim3(N_NODES / 128, FT / 128, 4), 256, 0, stream>>>(
        nullptr, Hmask, t2T, P, nullptr, N_EDGES / 4, 0, 64, N_EDGES, 512,
        (size_t)N_NODES * 512);

    // out = degv ⊙ (sum_s P) + bias
    final_kernel<<<(N_NODES * FT / 8) / 256, 256, 0, stream>>>(P, degv, bias, out);
}